// Round 10
// baseline (131.990 us; speedup 1.0000x reference)
//
#include <hip/hip_runtime.h>
#include <stdint.h>

typedef _Float16 half8  __attribute__((ext_vector_type(8)));
typedef __fp16   fp16x2 __attribute__((ext_vector_type(2)));
typedef float    floatx4 __attribute__((ext_vector_type(4)));
typedef uint32_t u32x4  __attribute__((ext_vector_type(4)));
typedef float    f4a    __attribute__((ext_vector_type(4), aligned(4)));  // 4B-aligned 16B load

union FragU { u32x4 v; uint32_t u[4]; half8 h; };
union H2U   { fp16x2 h; uint32_t u; };
union FU    { float f; uint32_t u; };

#define NT 256
#define NBLOCKS 1024                  // 4096 waves = 4 waves/SIMD resident
#define NWAVES (NBLOCKS * (NT / 64))  // 4096
#define ROWS_PER_GITER (NWAVES * 64)  // 262144

// Exact f16 hi/lo split, 3 VALU ops (numerics proven rounds 7-9):
// RTZ f16 of in-range f32 == mantissa truncation -> mask top-10 mantissa bits.
// Returns u32 with lo16 = f16(hi part), hi16 = f16(y - hi)  [exact residual].
__device__ __forceinline__ uint32_t splitpk(float y) {
    FU a; a.f = y; a.u &= 0xFFFFE000u;
    H2U r; r.h = __builtin_amdgcn_cvt_pkrtz(a.f, y - a.f);
    return r.u;
}

// ---------------- setup: build per-lane A-fragments (weights) into d_ws ----------------
// A-frag for mfma_f32_16x16x32_f16: lane l holds A[m=l&15][k=(l>>4)*8+e], e=0..7.
// Interleaved K: k=2i -> frag0=w_hi, frag1=w_lo ; k=2i+1 -> frag0=w_hi, frag1=0.
// Bias at k=30 (g==3,w==3): frag0=bias_hi, frag1=bias_lo (B supplies f16 1.0 there).
// L0 column table matches the lane load convention (even g: x0..x3 at +0; odd g: x3..x6 at +3):
//   g0 -> {x0,x1,x2,x3}, g1 -> {0(x3 dup), x4,x5,x6}, g2/g3 -> zeros (+bias slot).
__global__ void build_frags(const float* __restrict__ W0, const float* __restrict__ b0,
                            const float* __restrict__ W1, const float* __restrict__ b1,
                            const float* __restrict__ W2, const float* __restrict__ b2,
                            const float* __restrict__ W3, const float* __restrict__ b3,
                            const float* __restrict__ W4, const float* __restrict__ b4,
                            const float* __restrict__ W5, const float* __restrict__ b5,
                            const float* __restrict__ W6, const float* __restrict__ b6,
                            uint32_t* __restrict__ ws)
{
    const int l = threadIdx.x;
    if (l >= 64) return;
    const int m = l & 15, g = l >> 4;
    const float* Wm[5] = {W0, W1, W2, W3, W4};
    const float* bm[5] = {b0, b1, b2, b3, b4};

    for (int s = 0; s < 6; ++s) {
        const int fan_in = (s == 0) ? 7 : 12;
        const int mmax   = (s == 5) ? 1 : 12;
        const float wscale = (s == 0) ? 64.0f : (s == 5 ? (1.0f / 64.0f) : 1.0f);
        for (int w = 0; w < 4; ++w) {
            uint32_t u1 = 0, u2 = 0;
            if (g == 3 && w == 3) {
                float bv = 0.0f;
                if (m < mmax) {
                    if (s == 5) { bv = b6[0]; for (int c = 0; c < 6; ++c) bv = fmaf(b5[c], W6[c], bv); }
                    else        { bv = 64.0f * bm[s][m]; }
                }
                H2U hh; hh.h = __builtin_amdgcn_cvt_pkrtz(bv, 0.0f);
                float hf = (float)hh.h[0];
                H2U ll; ll.h = __builtin_amdgcn_cvt_pkrtz(bv - hf, 0.0f);
                u1 = hh.u; u2 = ll.u;
            } else {
                int i; bool ok;
                if (s == 0) { i = (g & 1) ? 3 + w : w; ok = ((g == 0) || (g == 1 && w > 0)) && (m < mmax); }
                else        { i = g * 4 + w;           ok = (i < fan_in) && (m < mmax); }
                if (ok) {
                    float wv;
                    if (s == 5) { wv = 0.0f; for (int c = 0; c < 6; ++c) wv = fmaf(W5[i * 6 + c], W6[c], wv); wv *= wscale; }
                    else        { wv = Wm[s][i * 12 + m] * wscale; }
                    H2U hh; hh.h = __builtin_amdgcn_cvt_pkrtz(wv, wv);        // (w_hi, w_hi)
                    float hf = (float)hh.h[0];
                    H2U ll; ll.h = __builtin_amdgcn_cvt_pkrtz(wv - hf, 0.0f); // (w_lo, 0)
                    u1 = hh.u; u2 = ll.u;
                }
            }
            ws[((s * 2 + 0) * 64 + l) * 4 + w] = u1;
            ws[((s * 2 + 1) * 64 + l) * 4 + w] = u2;
        }
    }
}

// 4 independent 16-row MFMA chains, PHASE-SPLIT per stage:
//   {build all 4 B-frags} -> {MFMA#1 st0..3} -> {MFMA#2 st0..3}
// so dependent MFMA pairs are 4 issues apart and the 4 chains interleave.
__device__ __forceinline__ void mlp16x4(const half8 (&A)[6][2], const f4a (&q)[4],
                                        floatx4 (&acc)[4], bool g3)
{
    const floatx4 fzero = {0.f, 0.f, 0.f, 0.f};
    FragU B[4];
    #pragma unroll
    for (int st = 0; st < 4; ++st) {
        B[st].u[0] = splitpk(q[st][0]);
        B[st].u[1] = splitpk(q[st][1]);
        B[st].u[2] = splitpk(q[st][2]);
        B[st].u[3] = g3 ? 0x00003C00u : splitpk(q[st][3]);   // bias slot: f16 1.0 at k=30
    }
    #pragma unroll
    for (int st = 0; st < 4; ++st)
        acc[st] = __builtin_amdgcn_mfma_f32_16x16x32_f16(A[0][0], B[st].h, fzero, 0, 0, 0);
    #pragma unroll
    for (int st = 0; st < 4; ++st)
        acc[st] = __builtin_amdgcn_mfma_f32_16x16x32_f16(A[0][1], B[st].h, acc[st], 0, 0, 0);

    #pragma unroll
    for (int s = 1; s <= 5; ++s) {
        #pragma unroll
        for (int st = 0; st < 4; ++st) {
            float y0 = acc[st][0], y1 = acc[st][1], y2 = acc[st][2], y3 = acc[st][3];
            if (s >= 2) {   // relu on outputs of layers 1..4
                y0 = fmaxf(y0, 0.f); y1 = fmaxf(y1, 0.f);
                y2 = fmaxf(y2, 0.f); y3 = fmaxf(y3, 0.f);
            }
            B[st].u[0] = splitpk(y0);
            B[st].u[1] = splitpk(y1);
            B[st].u[2] = splitpk(y2);
            B[st].u[3] = g3 ? 0x00003C00u : splitpk(y3);
        }
        #pragma unroll
        for (int st = 0; st < 4; ++st)
            acc[st] = __builtin_amdgcn_mfma_f32_16x16x32_f16(A[s][0], B[st].h, fzero, 0, 0, 0);
        #pragma unroll
        for (int st = 0; st < 4; ++st)
            acc[st] = __builtin_amdgcn_mfma_f32_16x16x32_f16(A[s][1], B[st].h, acc[st], 0, 0, 0);
    }
}

__global__ __launch_bounds__(NT, 4) void mlp_mfma(const float* __restrict__ in,
                                                  const uint32_t* __restrict__ ws,
                                                  float* __restrict__ out, int nrows)
{
    const int tid  = threadIdx.x;
    const int lane = tid & 63;
    const int m = lane & 15, g = lane >> 4;
    const bool godd = (g & 1) != 0;
    const bool g3   = (g == 3);

    // weight fragments: 48 regs (compiler places in AGPRs; MFMA-A reads are free)
    half8 A[6][2];
    #pragma unroll
    for (int s = 0; s < 6; ++s)
        #pragma unroll
        for (int f = 0; f < 2; ++f) {
            FragU fu;
            fu.v = *(const u32x4*)(ws + ((s * 2 + f) * 64 + lane) * 4);
            A[s][f] = fu.h;
        }

    const int wid  = (int)blockIdx.x * (NT / 64) + (tid >> 6);
    const int wuid = __builtin_amdgcn_readfirstlane(wid);
    const float* inp = in  + (size_t)wuid * (64 * 7);
    float*      outp = out + (size_t)wuid * 64;
    const int voffx = m * 7 + (godd ? 3 : 0);   // even groups x0..x3, odd groups x3..x6

    const int niter = nrows / ROWS_PER_GITER;
    const size_t S7 = (size_t)ROWS_PER_GITER * 7;

#define LOADQ(dst, base) { \
    _Pragma("unroll") \
    for (int st = 0; st < 4; ++st) dst[st] = *(const f4a*)((base) + voffx + st * (16 * 7)); }

    if (niter > 0) {
        f4a qa[4], qb[4];
        LOADQ(qa, inp);
        for (int t = 0; t < niter; t += 2) {
            const float* p1 = (t + 1 < niter) ? (inp + S7) : inp;   // clamped prefetch addr
            LOADQ(qb, p1);

            floatx4 accA[4];
            mlp16x4(A, qa, accA, g3);

            const float* p2 = (t + 2 < niter) ? (inp + 2 * S7) : inp;
            LOADQ(qa, p2);

            if (lane < 16) {
                #pragma unroll
                for (int st = 0; st < 4; ++st) outp[st * 16 + m] = accA[st][0];
            }

            if (t + 1 < niter) {
                floatx4 accB[4];
                mlp16x4(A, qb, accB, g3);
                if (lane < 16) {
                    #pragma unroll
                    for (int st = 0; st < 4; ++st) (outp + ROWS_PER_GITER)[st * 16 + m] = accB[st][0];
                }
            }
            inp  += 2 * S7;
            outp += 2 * (size_t)ROWS_PER_GITER;
        }
    }

    // tail (never taken for nrows = 8388608 = 32 * ROWS_PER_GITER; kept for safety)
    const int done = niter * ROWS_PER_GITER;
    if (done < nrows) {
        const int rowbase = done + wuid * 64;
        if (rowbase < nrows) {
            f4a q[4];
            #pragma unroll
            for (int st = 0; st < 4; ++st) {
                int row = rowbase + st * 16 + m;
                int rowc = row < nrows ? row : nrows - 1;
                q[st] = *(const f4a*)(in + (size_t)rowc * 7 + (godd ? 3 : 0));
            }
            floatx4 acc[4];
            mlp16x4(A, q, acc, g3);
            if (lane < 16) {
                #pragma unroll
                for (int st = 0; st < 4; ++st) {
                    int row = rowbase + st * 16 + m;
                    if (row < nrows) out[row] = acc[st][0];
                }
            }
        }
    }
#undef LOADQ
}

extern "C" void kernel_launch(void* const* d_in, const int* in_sizes, int n_in,
                              void* d_out, int out_size, void* d_ws, size_t ws_size,
                              hipStream_t stream) {
    const float* in = (const float*)d_in[0];
    const float* W0 = (const float*)d_in[1];  const float* b0 = (const float*)d_in[2];
    const float* W1 = (const float*)d_in[3];  const float* b1 = (const float*)d_in[4];
    const float* W2 = (const float*)d_in[5];  const float* b2 = (const float*)d_in[6];
    const float* W3 = (const float*)d_in[7];  const float* b3 = (const float*)d_in[8];
    const float* W4 = (const float*)d_in[9];  const float* b4 = (const float*)d_in[10];
    const float* W5 = (const float*)d_in[11]; const float* b5 = (const float*)d_in[12];
    const float* W6 = (const float*)d_in[13]; const float* b6 = (const float*)d_in[14];
    float* out = (float*)d_out;
    uint32_t* ws = (uint32_t*)d_ws;

    hipLaunchKernelGGL(build_frags, dim3(1), dim3(64), 0, stream,
                       W0, b0, W1, b1, W2, b2, W3, b3, W4, b4, W5, b5, W6, b6, ws);

    const int nrows = in_sizes[0] / 7;   // B*MS = 8388608
    hipLaunchKernelGGL(mlp_mfma, dim3(NBLOCKS), dim3(NT), 0, stream,
                       in, ws, out, nrows);
}